// Round 12
// baseline (305.159 us; speedup 1.0000x reference)
//
#include <hip/hip_runtime.h>

typedef short   bf16x8 __attribute__((ext_vector_type(8)));
typedef unsigned short u16x8 __attribute__((ext_vector_type(8)));
typedef float   f32x16 __attribute__((ext_vector_type(16)));

constexpr int NSUB  = 8;
constexpr int NCODE = 256;
constexpr int SDIM  = 96;
constexpr int EMB   = NSUB * SDIM;          // 768
constexpr float C_SHIFT = 192.0f;   // harmless shift baked into c2 (cancels in gaps)
constexpr float THR = 0.02f;        // validated recheck trigger (rounds 2-3-7-8-9-10)

constexpr int    CB_UNITS      = 8 * 6 * 2 * 64;                 // 6144 x 16B per subspace
constexpr size_t WS_FRAG_BYTES = (size_t)NSUB * CB_UNITS * 16;   // 786432
constexpr size_t WS_NEEDED     = WS_FRAG_BYTES + (size_t)NSUB * NCODE * 4;

__device__ __forceinline__ unsigned short f2bf(float v) {
    unsigned u = __builtin_bit_cast(unsigned, v);
    u = u + 0x7FFFu + ((u >> 16) & 1u);          // RNE
    return (unsigned short)(u >> 16);
}
__device__ __forceinline__ float bf2f(unsigned short h) {
    unsigned u = ((unsigned)h) << 16;
    return __builtin_bit_cast(float, u);
}

// ---------------- pre-kernel: pack codebook into ws (validated) ----------------
// frag unit u = ((t*6+s)*2+h)*64 + l : code=t*32+(l&31), k0=s*16+(l>>5)*8,
// value = h==0 ? hi : lo of (-cb). wsc2 = 0.5*||c||^2 + C_SHIFT (fp64).
__global__ __launch_bounds__(256) void pq_prep(const float* __restrict__ cb,
                                               unsigned short* __restrict__ wsf,
                                               float* __restrict__ wsc2)
{
    const int m   = (int)blockIdx.x;
    const int tid = (int)threadIdx.x;
    {
        const float* c = cb + ((size_t)m * NCODE + tid) * SDIM;
        double s = 0.0;
        for (int k = 0; k < SDIM; ++k) { double v = (double)c[k]; s += v * v; }
        wsc2[m * NCODE + tid] = (float)(0.5 * s + (double)C_SHIFT);
    }
    for (int i = 0; i < 24; ++i) {
        int u  = i * 256 + tid;
        int l  = u & 63;
        int c6 = u >> 6;
        int h  = c6 & 1; c6 >>= 1;
        int s  = c6 % 6;
        int t  = c6 / 6;
        int code = t * 32 + (l & 31);
        int k0   = s * 16 + (l >> 5) * 8;
        const float* src = cb + (size_t)m * NCODE * SDIM + (size_t)code * SDIM + k0;
        u16x8 o;
        #pragma unroll
        for (int j = 0; j < 8; ++j) {
            float v = -src[j];
            unsigned short hb = f2bf(v);
            o[j] = (h == 0) ? hb : f2bf(v - bf2f(hb));
        }
        *(u16x8*)(wsf + ((size_t)m * CB_UNITS + u) * 8) = o;
    }
}

// ------ main: one wave owns (m, 64 rows) as two 32-row sets sharing every ------
// ------ cb fragment load (halves the L2 cb stream). NO LDS, NO barriers. ------
// ------ Numerics byte-identical to validated round-10 path.              ------
__global__ __launch_bounds__(256) void pq_mfma10(
    const float* __restrict__ emb,
    const float* __restrict__ cb,
    const unsigned short* __restrict__ wsf,
    const float* __restrict__ wsc2,
    float* __restrict__ out,
    int nrows,
    int rowblks)
{
    const int tid  = (int)threadIdx.x;
    const int lane = tid & 63;
    const int hib  = lane >> 5;
    const int widx = (int)blockIdx.x * 4 + (tid >> 6);
    if (widx >= NSUB * rowblks) return;
    const int m    = widx / rowblks;            // waves of one m are contiguous
    const int rb   = widx % rowblks;
    const int row0 = rb * 64;

    const unsigned short* wb = wsf + (size_t)m * CB_UNITS * 8;
    const float* c2p = wsc2 + m * NCODE;

    // ---- x fragments for both row sets, hi/lo split in regs (validated layout) ----
    bf16x8 xhA[6], xlA[6], xhB[6], xlB[6];
    {
        int rA = row0 + (lane & 31);      if (rA >= nrows) rA = nrows - 1;
        int rB = row0 + 32 + (lane & 31); if (rB >= nrows) rB = nrows - 1;
        const float* xrA = emb + (size_t)rA * EMB + m * SDIM + hib * 8;
        const float* xrB = emb + (size_t)rB * EMB + m * SDIM + hib * 8;
        #pragma unroll
        for (int s = 0; s < 6; ++s) {
            float4 a0 = *(const float4*)(xrA + s * 16);
            float4 a1 = *(const float4*)(xrA + s * 16 + 4);
            float4 b0 = *(const float4*)(xrB + s * 16);
            float4 b1 = *(const float4*)(xrB + s * 16 + 4);
            float va[8] = { a0.x, a0.y, a0.z, a0.w, a1.x, a1.y, a1.z, a1.w };
            float vb[8] = { b0.x, b0.y, b0.z, b0.w, b1.x, b1.y, b1.z, b1.w };
            #pragma unroll
            for (int j = 0; j < 8; ++j) {
                unsigned short ha = f2bf(va[j]);
                xhA[s][j] = (short)ha;
                xlA[s][j] = (short)f2bf(va[j] - bf2f(ha));
                unsigned short hbv = f2bf(vb[j]);
                xhB[s][j] = (short)hbv;
                xlB[s][j] = (short)f2bf(vb[j] - bf2f(hbv));
            }
        }
    }

    // ---- 4 t-pairs; each pair's 24 cb loads feed 4 acc chains (2 rowsets) ----
    float b1A = 3.4e38f, b2A = 3.4e38f, b1B = 3.4e38f, b2B = 3.4e38f;
    int   i1A = 1 << 30, i2A = 1 << 30, i1B = 1 << 30, i2B = 1 << 30;
    #pragma unroll 1
    for (int p = 0; p < 4; ++p) {
        const int t0 = p * 2, t1 = t0 + 1;
        f32x16 a0A, a1A, a0B, a1B;
        #pragma unroll
        for (int rq = 0; rq < 4; ++rq) {
            float4 q0 = *(const float4*)(c2p + t0 * 32 + rq * 8 + hib * 4);
            float4 q1 = *(const float4*)(c2p + t1 * 32 + rq * 8 + hib * 4);
            a0A[rq*4+0]=q0.x; a0A[rq*4+1]=q0.y; a0A[rq*4+2]=q0.z; a0A[rq*4+3]=q0.w;
            a1A[rq*4+0]=q1.x; a1A[rq*4+1]=q1.y; a1A[rq*4+2]=q1.z; a1A[rq*4+3]=q1.w;
        }
        a0B = a0A; a1B = a1A;
        #pragma unroll
        for (int s = 0; s < 6; ++s) {
            bf16x8 ah0 = *(const bf16x8*)(wb + (size_t)((((t0 * 6 + s) * 2) + 0) * 64 + lane) * 8);
            bf16x8 al0 = *(const bf16x8*)(wb + (size_t)((((t0 * 6 + s) * 2) + 1) * 64 + lane) * 8);
            bf16x8 ah1 = *(const bf16x8*)(wb + (size_t)((((t1 * 6 + s) * 2) + 0) * 64 + lane) * 8);
            bf16x8 al1 = *(const bf16x8*)(wb + (size_t)((((t1 * 6 + s) * 2) + 1) * 64 + lane) * 8);
            a0A = __builtin_amdgcn_mfma_f32_32x32x16_bf16(ah0, xhA[s], a0A, 0, 0, 0);
            a0B = __builtin_amdgcn_mfma_f32_32x32x16_bf16(ah0, xhB[s], a0B, 0, 0, 0);
            a1A = __builtin_amdgcn_mfma_f32_32x32x16_bf16(ah1, xhA[s], a1A, 0, 0, 0);
            a1B = __builtin_amdgcn_mfma_f32_32x32x16_bf16(ah1, xhB[s], a1B, 0, 0, 0);
            a0A = __builtin_amdgcn_mfma_f32_32x32x16_bf16(al0, xhA[s], a0A, 0, 0, 0);
            a0B = __builtin_amdgcn_mfma_f32_32x32x16_bf16(al0, xhB[s], a0B, 0, 0, 0);
            a1A = __builtin_amdgcn_mfma_f32_32x32x16_bf16(al1, xhA[s], a1A, 0, 0, 0);
            a1B = __builtin_amdgcn_mfma_f32_32x32x16_bf16(al1, xhB[s], a1B, 0, 0, 0);
            a0A = __builtin_amdgcn_mfma_f32_32x32x16_bf16(ah0, xlA[s], a0A, 0, 0, 0);
            a0B = __builtin_amdgcn_mfma_f32_32x32x16_bf16(ah0, xlB[s], a0B, 0, 0, 0);
            a1A = __builtin_amdgcn_mfma_f32_32x32x16_bf16(ah1, xlA[s], a1A, 0, 0, 0);
            a1B = __builtin_amdgcn_mfma_f32_32x32x16_bf16(ah1, xlB[s], a1B, 0, 0, 0);
        }
        // serial scan (validated): ascending code order per lane, first-min ties
        #pragma unroll
        for (int r = 0; r < 16; ++r) {
            float sv = a0A[r];
            int   kv = t0 * 32 + (r & 3) + 8 * (r >> 2) + hib * 4;
            if (sv < b1A)      { b2A = b1A; i2A = i1A; b1A = sv; i1A = kv; }
            else if (sv < b2A) { b2A = sv; i2A = kv; }
        }
        #pragma unroll
        for (int r = 0; r < 16; ++r) {
            float sv = a1A[r];
            int   kv = t1 * 32 + (r & 3) + 8 * (r >> 2) + hib * 4;
            if (sv < b1A)      { b2A = b1A; i2A = i1A; b1A = sv; i1A = kv; }
            else if (sv < b2A) { b2A = sv; i2A = kv; }
        }
        #pragma unroll
        for (int r = 0; r < 16; ++r) {
            float sv = a0B[r];
            int   kv = t0 * 32 + (r & 3) + 8 * (r >> 2) + hib * 4;
            if (sv < b1B)      { b2B = b1B; i2B = i1B; b1B = sv; i1B = kv; }
            else if (sv < b2B) { b2B = sv; i2B = kv; }
        }
        #pragma unroll
        for (int r = 0; r < 16; ++r) {
            float sv = a1B[r];
            int   kv = t1 * 32 + (r & 3) + 8 * (r >> 2) + hib * 4;
            if (sv < b1B)      { b2B = b1B; i2B = i1B; b1B = sv; i1B = kv; }
            else if (sv < b2B) { b2B = sv; i2B = kv; }
        }
    }
    {   // merge lane^32 partner for rowset A (validated code)
        float ob1 = __shfl_xor(b1A, 32);
        int   oi1 = __shfl_xor(i1A, 32);
        float ob2 = __shfl_xor(b2A, 32);
        int   oi2 = __shfl_xor(i2A, 32);
        bool o1_better = (ob1 < b1A) || (ob1 == b1A && oi1 < i1A);
        if (o1_better) {
            bool mine_better = (b1A < ob2) || (b1A == ob2 && i1A < oi2);
            if (mine_better) { b2A = b1A; i2A = i1A; } else { b2A = ob2; i2A = oi2; }
            b1A = ob1; i1A = oi1;
        } else {
            if ((ob1 < b2A) || (ob1 == b2A && oi1 < i2A)) { b2A = ob1; i2A = oi1; }
        }
    }
    {   // merge lane^32 partner for rowset B (validated code)
        float ob1 = __shfl_xor(b1B, 32);
        int   oi1 = __shfl_xor(i1B, 32);
        float ob2 = __shfl_xor(b2B, 32);
        int   oi2 = __shfl_xor(i2B, 32);
        bool o1_better = (ob1 < b1B) || (ob1 == b1B && oi1 < i1B);
        if (o1_better) {
            bool mine_better = (b1B < ob2) || (b1B == ob2 && i1B < oi2);
            if (mine_better) { b2B = b1B; i2B = i1B; } else { b2B = ob2; i2B = oi2; }
            b1B = ob1; i1B = oi1;
        } else {
            if ((ob1 < b2B) || (ob1 == b2B && oi1 < i2B)) { b2B = ob1; i2B = oi1; }
        }
    }

    // ---- per-lane row assignment: lane l owns row row0+l (A half / B half) ----
    float gb1 = (lane < 32) ? b1A : b1B;
    float gb2 = (lane < 32) ? b2A : b2B;
    int   gi1 = (lane < 32) ? i1A : i1B;
    int   gi2 = (lane < 32) ? i2A : i2B;
    {   // cheap top-2 fp64 recheck (exact; ~1-2% trigger; uniform 96-iter loop)
        int grow = row0 + lane;
        if (grow < nrows && (gb2 - gb1 < THR)) {
            const float* xr = emb + (size_t)grow * EMB + m * SDIM;
            const float* ca = cb + ((size_t)m * NCODE + gi1) * SDIM;
            const float* cbv = cb + ((size_t)m * NCODE + gi2) * SDIM;
            double da = 0.0, db = 0.0;
            for (int kk = 0; kk < SDIM; ++kk) {
                double ea = (double)xr[kk] - (double)ca[kk];
                double eb = (double)xr[kk] - (double)cbv[kk];
                da += ea * ea; db += eb * eb;
            }
            if (db < da || (db == da && gi2 < gi1)) gi1 = gi2;
        }
    }

    // ---- gather + coalesced write-out (24-lane 384B runs per row, 64 rows) ----
    #pragma unroll
    for (int ii = 0; ii < 24; ++ii) {
        int Q = ii * 64 + lane;                 // 1536 = 64 rows x 24 float4
        int r = Q / 24, f = Q % 24;
        int grow = row0 + r;
        int k = __shfl(gi1, r);                 // lane r holds row row0+r winner
        if (grow < nrows) {
            float4 v = *(const float4*)(cb + ((size_t)m * NCODE + k) * SDIM + f * 4);
            *(float4*)(out + (size_t)grow * EMB + m * SDIM + f * 4) = v;
        }
    }
}

// ---------------- fallback (round-2 kernel, validated) ----------------
__global__ __launch_bounds__(256) void pq_argmin_kernel(
    const float* __restrict__ emb, const float* __restrict__ cb,
    float* __restrict__ out, int nrows)
{
    const int m   = (int)(blockIdx.x & 7);
    const int row = (int)(blockIdx.x >> 3) * 256 + (int)threadIdx.x;
    const float* __restrict__ cbm = cb + (size_t)m * (NCODE * SDIM);
    __shared__ float half_c2[NCODE];
    {
        const int k = (int)threadIdx.x;
        const float* c = cbm + k * SDIM;
        float s = 0.f;
        #pragma unroll
        for (int i = 0; i < SDIM; i += 4) {
            const float4 v = *reinterpret_cast<const float4*>(c + i);
            s = fmaf(v.x, v.x, s); s = fmaf(v.y, v.y, s);
            s = fmaf(v.z, v.z, s); s = fmaf(v.w, v.w, s);
        }
        half_c2[k] = 0.5f * s;
    }
    __syncthreads();
    if (row >= nrows) return;
    float x[SDIM];
    {
        const float* xr = emb + (size_t)row * EMB + m * SDIM;
        #pragma unroll
        for (int i = 0; i < SDIM; i += 4) {
            const float4 v = *reinterpret_cast<const float4*>(xr + i);
            x[i+0] = v.x; x[i+1] = v.y; x[i+2] = v.z; x[i+3] = v.w;
        }
    }
    float best = 3.4e38f, best2 = 3.4e38f;
    int bestk = 0, bestk2 = 0;
    #pragma unroll 1
    for (int k = 0; k < NCODE; k += 4) {
        const float* c0 = cbm + (k + 0) * SDIM;
        const float* c1 = cbm + (k + 1) * SDIM;
        const float* c2 = cbm + (k + 2) * SDIM;
        const float* c3 = cbm + (k + 3) * SDIM;
        float a0 = 0.f, a1 = 0.f, a2 = 0.f, a3 = 0.f;
        #pragma unroll
        for (int i = 0; i < SDIM; i += 4) {
            const float4 v0 = *reinterpret_cast<const float4*>(c0 + i);
            const float4 v1 = *reinterpret_cast<const float4*>(c1 + i);
            const float4 v2 = *reinterpret_cast<const float4*>(c2 + i);
            const float4 v3 = *reinterpret_cast<const float4*>(c3 + i);
            a0 = fmaf(x[i+0], v0.x, a0); a0 = fmaf(x[i+1], v0.y, a0);
            a0 = fmaf(x[i+2], v0.z, a0); a0 = fmaf(x[i+3], v0.w, a0);
            a1 = fmaf(x[i+0], v1.x, a1); a1 = fmaf(x[i+1], v1.y, a1);
            a1 = fmaf(x[i+2], v1.z, a1); a1 = fmaf(x[i+3], v1.w, a1);
            a2 = fmaf(x[i+0], v2.x, a2); a2 = fmaf(x[i+1], v2.y, a2);
            a2 = fmaf(x[i+2], v2.z, a2); a2 = fmaf(x[i+3], v2.w, a2);
            a3 = fmaf(x[i+0], v3.x, a3); a3 = fmaf(x[i+1], v3.y, a3);
            a3 = fmaf(x[i+2], v3.z, a3); a3 = fmaf(x[i+3], v3.w, a3);
        }
        const float s[4] = { half_c2[k+0] - a0, half_c2[k+1] - a1,
                             half_c2[k+2] - a2, half_c2[k+3] - a3 };
        #pragma unroll
        for (int j = 0; j < 4; ++j) {
            if (s[j] < best)       { best2 = best; bestk2 = bestk; best = s[j]; bestk = k + j; }
            else if (s[j] < best2) { best2 = s[j]; bestk2 = k + j; }
        }
    }
    if (best2 - best < 0.02f) {
        const float* ca = cbm + bestk  * SDIM;
        const float* cbv = cbm + bestk2 * SDIM;
        double da = 0.0, db = 0.0;
        for (int i = 0; i < SDIM; ++i) {
            const double ea = (double)x[i] - (double)ca[i];
            const double eb = (double)x[i] - (double)cbv[i];
            da += ea * ea; db += eb * eb;
        }
        if (db < da || (db == da && bestk2 < bestk)) bestk = bestk2;
    }
    const float* cbest = cbm + bestk * SDIM;
    float* o = out + (size_t)row * EMB + m * SDIM;
    #pragma unroll
    for (int i = 0; i < SDIM; i += 4)
        *reinterpret_cast<float4*>(o + i) = *reinterpret_cast<const float4*>(cbest + i);
}

extern "C" void kernel_launch(void* const* d_in, const int* in_sizes, int n_in,
                              void* d_out, int out_size, void* d_ws, size_t ws_size,
                              hipStream_t stream) {
    const float* emb = (const float*)d_in[0];
    const float* cb  = (const float*)d_in[1];
    float* out = (float*)d_out;
    const int nrows = in_sizes[0] / EMB;    // 65536

    if (ws_size < WS_NEEDED) {
        const int rowBlocks = (nrows + 255) / 256;
        pq_argmin_kernel<<<dim3(rowBlocks * NSUB), dim3(256), 0, stream>>>(emb, cb, out, nrows);
        return;
    }

    unsigned short* wsf = (unsigned short*)d_ws;
    float* wsc2 = (float*)((char*)d_ws + WS_FRAG_BYTES);

    pq_prep<<<dim3(NSUB), dim3(256), 0, stream>>>(cb, wsf, wsc2);

    const int rowblks = (nrows + 63) / 64;              // 1024
    const int nwaves  = rowblks * NSUB;                 // 8192
    const int nb      = (nwaves + 3) / 4;               // 2048 blocks of 256
    pq_mfma10<<<dim3(nb), dim3(256), 0, stream>>>(emb, cb, wsf, wsc2, out, nrows, rowblks);
}

// Round 13
// 253.957 us; speedup vs baseline: 1.2016x; 1.2016x over previous
//
#include <hip/hip_runtime.h>

typedef short   bf16x8 __attribute__((ext_vector_type(8)));
typedef unsigned short u16x8 __attribute__((ext_vector_type(8)));
typedef float   f32x16 __attribute__((ext_vector_type(16)));

constexpr int NSUB  = 8;
constexpr int NCODE = 256;
constexpr int SDIM  = 96;
constexpr int EMB   = NSUB * SDIM;          // 768
constexpr float C_SHIFT = 192.0f;   // harmless shift baked into c2 (cancels in gaps)
constexpr float THR = 0.02f;        // validated recheck trigger (rounds 2-3-7..10)

constexpr int    CB_UNITS      = 8 * 6 * 2 * 64;                 // 6144 x 16B per subspace
constexpr size_t WS_FRAG_BYTES = (size_t)NSUB * CB_UNITS * 16;   // 786432
constexpr size_t WS_NEEDED     = WS_FRAG_BYTES + (size_t)NSUB * NCODE * 4;

__device__ __forceinline__ unsigned short f2bf(float v) {
    unsigned u = __builtin_bit_cast(unsigned, v);
    u = u + 0x7FFFu + ((u >> 16) & 1u);          // RNE
    return (unsigned short)(u >> 16);
}
__device__ __forceinline__ float bf2f(unsigned short h) {
    unsigned u = ((unsigned)h) << 16;
    return __builtin_bit_cast(float, u);
}

// index-aware top-2 merge (validated lane^32-merge rule, reused for pair merges)
__device__ __forceinline__ void merge_top2(float& b1, int& i1, float& b2, int& i2,
                                           float ob1, int oi1, float ob2, int oi2) {
    bool o1_better = (ob1 < b1) || (ob1 == b1 && oi1 < i1);
    if (o1_better) {
        bool mine_better = (b1 < ob2) || (b1 == ob2 && i1 < oi2);
        if (mine_better) { b2 = b1; i2 = i1; } else { b2 = ob2; i2 = oi2; }
        b1 = ob1; i1 = oi1;
    } else {
        if ((ob1 < b2) || (ob1 == b2 && oi1 < i2)) { b2 = ob1; i2 = oi1; }
    }
}

// ---------------- pre-kernel: pack codebook into ws (validated) ----------------
// frag unit u = ((t*6+s)*2+h)*64 + l : code=t*32+(l&31), k0=s*16+(l>>5)*8,
// value = h==0 ? hi : lo of (-cb). wsc2 = 0.5*||c||^2 + C_SHIFT (fp64).
__global__ __launch_bounds__(256) void pq_prep(const float* __restrict__ cb,
                                               unsigned short* __restrict__ wsf,
                                               float* __restrict__ wsc2)
{
    const int m   = (int)blockIdx.x;
    const int tid = (int)threadIdx.x;
    {
        const float* c = cb + ((size_t)m * NCODE + tid) * SDIM;
        double s = 0.0;
        for (int k = 0; k < SDIM; ++k) { double v = (double)c[k]; s += v * v; }
        wsc2[m * NCODE + tid] = (float)(0.5 * s + (double)C_SHIFT);
    }
    for (int i = 0; i < 24; ++i) {
        int u  = i * 256 + tid;
        int l  = u & 63;
        int c6 = u >> 6;
        int h  = c6 & 1; c6 >>= 1;
        int s  = c6 % 6;
        int t  = c6 / 6;
        int code = t * 32 + (l & 31);
        int k0   = s * 16 + (l >> 5) * 8;
        const float* src = cb + (size_t)m * NCODE * SDIM + (size_t)code * SDIM + k0;
        u16x8 o;
        #pragma unroll
        for (int j = 0; j < 8; ++j) {
            float v = -src[j];
            unsigned short hb = f2bf(v);
            o[j] = (h == 0) ? hb : f2bf(v - bf2f(hb));
        }
        *(u16x8*)(wsf + ((size_t)m * CB_UNITS + u) * 8) = o;
    }
}

// ------ main: one wave owns (m, 32 rows); NO LDS/barriers (R10 shape).   ------
// ------ Fully-unrolled pairs + independent per-pair top-2 scans (ILP).   ------
__global__ __launch_bounds__(256) void pq_mfma11(
    const float* __restrict__ emb,
    const float* __restrict__ cb,
    const unsigned short* __restrict__ wsf,
    const float* __restrict__ wsc2,
    float* __restrict__ out,
    int nrows,
    int rowblks)
{
    const int tid  = (int)threadIdx.x;
    const int lane = tid & 63;
    const int hib  = lane >> 5;
    const int widx = (int)blockIdx.x * 4 + (tid >> 6);
    if (widx >= NSUB * rowblks) return;
    const int m    = widx / rowblks;            // waves of one m are contiguous
    const int rb   = widx % rowblks;
    const int row0 = rb * 32;

    const unsigned short* wb = wsf + (size_t)m * CB_UNITS * 8;
    const float* c2p = wsc2 + m * NCODE;

    // ---- x fragments: trunc-hi / RNE-lo split, in regs (validated B layout) ----
    bf16x8 xh[6], xl[6];
    {
        int r = row0 + (lane & 31);
        if (r >= nrows) r = nrows - 1;
        const float* xr = emb + (size_t)r * EMB + m * SDIM + hib * 8;
        #pragma unroll
        for (int s = 0; s < 6; ++s) {
            float4 v0 = *(const float4*)(xr + s * 16);
            float4 v1 = *(const float4*)(xr + s * 16 + 4);
            float v[8] = { v0.x, v0.y, v0.z, v0.w, v1.x, v1.y, v1.z, v1.w };
            #pragma unroll
            for (int j = 0; j < 8; ++j) {
                unsigned u = __builtin_bit_cast(unsigned, v[j]);
                xh[s][j] = (short)(unsigned short)(u >> 16);      // truncated hi
                float hif = __builtin_bit_cast(float, u & 0xFFFF0000u);
                xl[s][j] = (short)f2bf(v[j] - hif);               // RNE remainder
            }
        }
    }

    // ---- one pair = codes [t0*32, t0*32+64): 24 cb loads, 18 MFMA, local scan ----
    auto do_pair = [&](int t0, float& B1, int& I1, float& B2, int& I2) {
        const int t1 = t0 + 1;
        f32x16 a0, a1;
        #pragma unroll
        for (int rq = 0; rq < 4; ++rq) {
            float4 q0 = *(const float4*)(c2p + t0 * 32 + rq * 8 + hib * 4);
            float4 q1 = *(const float4*)(c2p + t1 * 32 + rq * 8 + hib * 4);
            a0[rq*4+0]=q0.x; a0[rq*4+1]=q0.y; a0[rq*4+2]=q0.z; a0[rq*4+3]=q0.w;
            a1[rq*4+0]=q1.x; a1[rq*4+1]=q1.y; a1[rq*4+2]=q1.z; a1[rq*4+3]=q1.w;
        }
        #pragma unroll
        for (int s = 0; s < 6; ++s) {
            bf16x8 ah0 = *(const bf16x8*)(wb + (size_t)((((t0 * 6 + s) * 2) + 0) * 64 + lane) * 8);
            bf16x8 al0 = *(const bf16x8*)(wb + (size_t)((((t0 * 6 + s) * 2) + 1) * 64 + lane) * 8);
            bf16x8 ah1 = *(const bf16x8*)(wb + (size_t)((((t1 * 6 + s) * 2) + 0) * 64 + lane) * 8);
            bf16x8 al1 = *(const bf16x8*)(wb + (size_t)((((t1 * 6 + s) * 2) + 1) * 64 + lane) * 8);
            a0 = __builtin_amdgcn_mfma_f32_32x32x16_bf16(ah0, xh[s], a0, 0, 0, 0);
            a1 = __builtin_amdgcn_mfma_f32_32x32x16_bf16(ah1, xh[s], a1, 0, 0, 0);
            a0 = __builtin_amdgcn_mfma_f32_32x32x16_bf16(al0, xh[s], a0, 0, 0, 0);
            a1 = __builtin_amdgcn_mfma_f32_32x32x16_bf16(al1, xh[s], a1, 0, 0, 0);
            a0 = __builtin_amdgcn_mfma_f32_32x32x16_bf16(ah0, xl[s], a0, 0, 0, 0);
            a1 = __builtin_amdgcn_mfma_f32_32x32x16_bf16(ah1, xl[s], a1, 0, 0, 0);
        }
        // serial scan within pair (validated order: a0 then a1, ascending codes)
        float b1 = 3.4e38f, b2 = 3.4e38f;
        int   i1 = 1 << 30, i2 = 1 << 30;
        #pragma unroll
        for (int r = 0; r < 16; ++r) {
            float sv = a0[r];
            int   kv = t0 * 32 + (r & 3) + 8 * (r >> 2) + hib * 4;
            if (sv < b1)      { b2 = b1; i2 = i1; b1 = sv; i1 = kv; }
            else if (sv < b2) { b2 = sv; i2 = kv; }
        }
        #pragma unroll
        for (int r = 0; r < 16; ++r) {
            float sv = a1[r];
            int   kv = t1 * 32 + (r & 3) + 8 * (r >> 2) + hib * 4;
            if (sv < b1)      { b2 = b1; i2 = i1; b1 = sv; i1 = kv; }
            else if (sv < b2) { b2 = sv; i2 = kv; }
        }
        B1 = b1; I1 = i1; B2 = b2; I2 = i2;
    };

    // 4 independent pair chains (compiler may interleave loads/MFMA/scans)
    float pb0, pb0b, pb1, pb1b, pb2, pb2b, pb3, pb3b;
    int   pi0, pi0b, pi1, pi1b, pi2, pi2b, pi3, pi3b;
    do_pair(0, pb0, pi0, pb0b, pi0b);
    do_pair(2, pb1, pi1, pb1b, pi1b);
    do_pair(4, pb2, pi2, pb2b, pi2b);
    do_pair(6, pb3, pi3, pb3b, pi3b);

    // merge pairs (index-aware: equals serial-scan result incl. tie rule)
    merge_top2(pb0, pi0, pb0b, pi0b, pb1, pi1, pb1b, pi1b);
    merge_top2(pb2, pi2, pb2b, pi2b, pb3, pi3, pb3b, pi3b);
    merge_top2(pb0, pi0, pb0b, pi0b, pb2, pi2, pb2b, pi2b);

    // merge lane^32 partner (same rows, other hib codes)
    {
        float ob1 = __shfl_xor(pb0, 32);
        int   oi1 = __shfl_xor(pi0, 32);
        float ob2 = __shfl_xor(pb0b, 32);
        int   oi2 = __shfl_xor(pi0b, 32);
        merge_top2(pb0, pi0, pb0b, pi0b, ob1, oi1, ob2, oi2);
    }

    int i1 = pi0;
    // ---- cheap top-2 fp64 recheck (exact; ~1-2% trigger; uniform 96-iter loop) ----
    {
        int grow = row0 + (lane & 31);
        if (lane < 32 && grow < nrows && (pb0b - pb0 < THR)) {
            const float* xr = emb + (size_t)grow * EMB + m * SDIM;
            const float* ca = cb + ((size_t)m * NCODE + i1) * SDIM;
            const float* cbv = cb + ((size_t)m * NCODE + pi0b) * SDIM;
            double da = 0.0, db = 0.0;
            for (int kk = 0; kk < SDIM; ++kk) {
                double ea = (double)xr[kk] - (double)ca[kk];
                double eb = (double)xr[kk] - (double)cbv[kk];
                da += ea * ea; db += eb * eb;
            }
            if (db < da || (db == da && pi0b < i1)) i1 = pi0b;
        }
    }

    // ---- gather + coalesced write-out (24-lane 384B runs per row) ----
    #pragma unroll
    for (int ii = 0; ii < 12; ++ii) {
        int Q = ii * 64 + lane;                 // 768 = 32 rows x 24 float4
        int r = Q / 24, f = Q % 24;
        int grow = row0 + r;
        int k = __shfl(i1, r);                  // winner held by lane r (<32)
        if (grow < nrows) {
            float4 v = *(const float4*)(cb + ((size_t)m * NCODE + k) * SDIM + f * 4);
            *(float4*)(out + (size_t)grow * EMB + m * SDIM + f * 4) = v;
        }
    }
}

// ---------------- fallback (round-2 kernel, validated) ----------------
__global__ __launch_bounds__(256) void pq_argmin_kernel(
    const float* __restrict__ emb, const float* __restrict__ cb,
    float* __restrict__ out, int nrows)
{
    const int m   = (int)(blockIdx.x & 7);
    const int row = (int)(blockIdx.x >> 3) * 256 + (int)threadIdx.x;
    const float* __restrict__ cbm = cb + (size_t)m * (NCODE * SDIM);
    __shared__ float half_c2[NCODE];
    {
        const int k = (int)threadIdx.x;
        const float* c = cbm + k * SDIM;
        float s = 0.f;
        #pragma unroll
        for (int i = 0; i < SDIM; i += 4) {
            const float4 v = *reinterpret_cast<const float4*>(c + i);
            s = fmaf(v.x, v.x, s); s = fmaf(v.y, v.y, s);
            s = fmaf(v.z, v.z, s); s = fmaf(v.w, v.w, s);
        }
        half_c2[k] = 0.5f * s;
    }
    __syncthreads();
    if (row >= nrows) return;
    float x[SDIM];
    {
        const float* xr = emb + (size_t)row * EMB + m * SDIM;
        #pragma unroll
        for (int i = 0; i < SDIM; i += 4) {
            const float4 v = *reinterpret_cast<const float4*>(xr + i);
            x[i+0] = v.x; x[i+1] = v.y; x[i+2] = v.z; x[i+3] = v.w;
        }
    }
    float best = 3.4e38f, best2 = 3.4e38f;
    int bestk = 0, bestk2 = 0;
    #pragma unroll 1
    for (int k = 0; k < NCODE; k += 4) {
        const float* c0 = cbm + (k + 0) * SDIM;
        const float* c1 = cbm + (k + 1) * SDIM;
        const float* c2 = cbm + (k + 2) * SDIM;
        const float* c3 = cbm + (k + 3) * SDIM;
        float a0 = 0.f, a1 = 0.f, a2 = 0.f, a3 = 0.f;
        #pragma unroll
        for (int i = 0; i < SDIM; i += 4) {
            const float4 v0 = *reinterpret_cast<const float4*>(c0 + i);
            const float4 v1 = *reinterpret_cast<const float4*>(c1 + i);
            const float4 v2 = *reinterpret_cast<const float4*>(c2 + i);
            const float4 v3 = *reinterpret_cast<const float4*>(c3 + i);
            a0 = fmaf(x[i+0], v0.x, a0); a0 = fmaf(x[i+1], v0.y, a0);
            a0 = fmaf(x[i+2], v0.z, a0); a0 = fmaf(x[i+3], v0.w, a0);
            a1 = fmaf(x[i+0], v1.x, a1); a1 = fmaf(x[i+1], v1.y, a1);
            a1 = fmaf(x[i+2], v1.z, a1); a1 = fmaf(x[i+3], v1.w, a1);
            a2 = fmaf(x[i+0], v2.x, a2); a2 = fmaf(x[i+1], v2.y, a2);
            a2 = fmaf(x[i+2], v2.z, a2); a2 = fmaf(x[i+3], v2.w, a2);
            a3 = fmaf(x[i+0], v3.x, a3); a3 = fmaf(x[i+1], v3.y, a3);
            a3 = fmaf(x[i+2], v3.z, a3); a3 = fmaf(x[i+3], v3.w, a3);
        }
        const float s[4] = { half_c2[k+0] - a0, half_c2[k+1] - a1,
                             half_c2[k+2] - a2, half_c2[k+3] - a3 };
        #pragma unroll
        for (int j = 0; j < 4; ++j) {
            if (s[j] < best)       { best2 = best; bestk2 = bestk; best = s[j]; bestk = k + j; }
            else if (s[j] < best2) { best2 = s[j]; bestk2 = k + j; }
        }
    }
    if (best2 - best < 0.02f) {
        const float* ca = cbm + bestk  * SDIM;
        const float* cbv = cbm + bestk2 * SDIM;
        double da = 0.0, db = 0.0;
        for (int i = 0; i < SDIM; ++i) {
            const double ea = (double)x[i] - (double)ca[i];
            const double eb = (double)x[i] - (double)cbv[i];
            da += ea * ea; db += eb * eb;
        }
        if (db < da || (db == da && bestk2 < bestk)) bestk = bestk2;
    }
    const float* cbest = cbm + bestk * SDIM;
    float* o = out + (size_t)row * EMB + m * SDIM;
    #pragma unroll
    for (int i = 0; i < SDIM; i += 4)
        *reinterpret_cast<float4*>(o + i) = *reinterpret_cast<const float4*>(cbest + i);
}

extern "C" void kernel_launch(void* const* d_in, const int* in_sizes, int n_in,
                              void* d_out, int out_size, void* d_ws, size_t ws_size,
                              hipStream_t stream) {
    const float* emb = (const float*)d_in[0];
    const float* cb  = (const float*)d_in[1];
    float* out = (float*)d_out;
    const int nrows = in_sizes[0] / EMB;    // 65536

    if (ws_size < WS_NEEDED) {
        const int rowBlocks = (nrows + 255) / 256;
        pq_argmin_kernel<<<dim3(rowBlocks * NSUB), dim3(256), 0, stream>>>(emb, cb, out, nrows);
        return;
    }

    unsigned short* wsf = (unsigned short*)d_ws;
    float* wsc2 = (float*)((char*)d_ws + WS_FRAG_BYTES);

    pq_prep<<<dim3(NSUB), dim3(256), 0, stream>>>(cb, wsf, wsc2);

    const int rowblks = (nrows + 31) / 32;              // 2048
    const int nwaves  = rowblks * NSUB;                 // 16384
    const int nb      = (nwaves + 3) / 4;               // 4096 blocks of 256
    pq_mfma11<<<dim3(nb), dim3(256), 0, stream>>>(emb, cb, wsf, wsc2, out, nrows, rowblks);
}

// Round 14
// 206.326 us; speedup vs baseline: 1.4790x; 1.2309x over previous
//
#include <hip/hip_runtime.h>

typedef short   bf16x8 __attribute__((ext_vector_type(8)));
typedef unsigned short u16x8 __attribute__((ext_vector_type(8)));
typedef float   f32x16 __attribute__((ext_vector_type(16)));

constexpr int NSUB  = 8;
constexpr int NCODE = 256;
constexpr int SDIM  = 96;
constexpr int EMB   = NSUB * SDIM;          // 768
constexpr float C_SHIFT = 192.0f;   // harmless shift baked into c2 (cancels in gaps)
constexpr float THR = 0.02f;        // validated recheck trigger (rounds 2-3-7..10)

constexpr int    CB_UNITS      = 8 * 6 * 2 * 64;                 // 6144 x 16B per subspace
constexpr size_t WS_FRAG_BYTES = (size_t)NSUB * CB_UNITS * 16;   // 786432
constexpr size_t WS_NEEDED     = WS_FRAG_BYTES + (size_t)NSUB * NCODE * 4;

__device__ __forceinline__ unsigned short f2bf(float v) {
    unsigned u = __builtin_bit_cast(unsigned, v);
    u = u + 0x7FFFu + ((u >> 16) & 1u);          // RNE
    return (unsigned short)(u >> 16);
}
__device__ __forceinline__ float bf2f(unsigned short h) {
    unsigned u = ((unsigned)h) << 16;
    return __builtin_bit_cast(float, u);
}

// ---------------- pre-kernel: pack codebook into ws (validated) ----------------
// frag unit u = ((t*6+s)*2+h)*64 + l : code=t*32+(l&31), k0=s*16+(l>>5)*8,
// value = h==0 ? hi : lo of (-cb). wsc2 = 0.5*||c||^2 + C_SHIFT (fp64).
__global__ __launch_bounds__(256) void pq_prep(const float* __restrict__ cb,
                                               unsigned short* __restrict__ wsf,
                                               float* __restrict__ wsc2)
{
    const int m   = (int)blockIdx.x;
    const int tid = (int)threadIdx.x;
    {
        const float* c = cb + ((size_t)m * NCODE + tid) * SDIM;
        double s = 0.0;
        for (int k = 0; k < SDIM; ++k) { double v = (double)c[k]; s += v * v; }
        wsc2[m * NCODE + tid] = (float)(0.5 * s + (double)C_SHIFT);
    }
    for (int i = 0; i < 24; ++i) {
        int u  = i * 256 + tid;
        int l  = u & 63;
        int c6 = u >> 6;
        int h  = c6 & 1; c6 >>= 1;
        int s  = c6 % 6;
        int t  = c6 / 6;
        int code = t * 32 + (l & 31);
        int k0   = s * 16 + (l >> 5) * 8;
        const float* src = cb + (size_t)m * NCODE * SDIM + (size_t)code * SDIM + k0;
        u16x8 o;
        #pragma unroll
        for (int j = 0; j < 8; ++j) {
            float v = -src[j];
            unsigned short hb = f2bf(v);
            o[j] = (h == 0) ? hb : f2bf(v - bf2f(hb));
        }
        *(u16x8*)(wsf + ((size_t)m * CB_UNITS + u) * 8) = o;
    }
}

// ------ main: one wave owns (m, 32 rows). NO LDS, NO barriers.           ------
// ------ Byte-identical numerics to validated R10; 128-thr blocks (finer  ------
// ------ CU packing) + s_setprio around the MFMA cluster (T5).            ------
__global__ __launch_bounds__(128, 3) void pq_mfma12(
    const float* __restrict__ emb,
    const float* __restrict__ cb,
    const unsigned short* __restrict__ wsf,
    const float* __restrict__ wsc2,
    float* __restrict__ out,
    int nrows,
    int rowblks)
{
    const int tid  = (int)threadIdx.x;
    const int lane = tid & 63;
    const int hib  = lane >> 5;
    const int widx = (int)blockIdx.x * 2 + (tid >> 6);
    if (widx >= NSUB * rowblks) return;
    const int m    = widx / rowblks;            // waves of one m are contiguous
    const int rb   = widx % rowblks;
    const int row0 = rb * 32;

    const unsigned short* wb = wsf + (size_t)m * CB_UNITS * 8;
    const float* c2p = wsc2 + m * NCODE;

    // ---- load this lane's x fragments straight from emb; hi/lo split in regs ----
    // lane l holds row (l&31), dims s*16 + (l>>5)*8 + [0..8)  (validated B layout)
    bf16x8 xh[6], xl[6];
    {
        int r = row0 + (lane & 31);
        if (r >= nrows) r = nrows - 1;
        const float* xr = emb + (size_t)r * EMB + m * SDIM + hib * 8;
        #pragma unroll
        for (int s = 0; s < 6; ++s) {
            float4 v0 = *(const float4*)(xr + s * 16);
            float4 v1 = *(const float4*)(xr + s * 16 + 4);
            float v[8] = { v0.x, v0.y, v0.z, v0.w, v1.x, v1.y, v1.z, v1.w };
            #pragma unroll
            for (int j = 0; j < 8; ++j) {
                unsigned short hb = f2bf(v[j]);
                xh[s][j] = (short)hb;
                xl[s][j] = (short)f2bf(v[j] - bf2f(hb));
            }
        }
    }

    // ---- 4 t-pairs: acc init from c2, 36 MFMA, serial scan (code-ascending) ----
    float b1 = 3.4e38f, b2 = 3.4e38f;
    int   i1 = 1 << 30, i2 = 1 << 30;
    #pragma unroll 1
    for (int p = 0; p < 4; ++p) {
        const int t0 = p * 2, t1 = t0 + 1;
        f32x16 a0, a1;
        #pragma unroll
        for (int rq = 0; rq < 4; ++rq) {
            float4 q0 = *(const float4*)(c2p + t0 * 32 + rq * 8 + hib * 4);
            float4 q1 = *(const float4*)(c2p + t1 * 32 + rq * 8 + hib * 4);
            a0[rq*4+0]=q0.x; a0[rq*4+1]=q0.y; a0[rq*4+2]=q0.z; a0[rq*4+3]=q0.w;
            a1[rq*4+0]=q1.x; a1[rq*4+1]=q1.y; a1[rq*4+2]=q1.z; a1[rq*4+3]=q1.w;
        }
        __builtin_amdgcn_s_setprio(1);
        #pragma unroll
        for (int s = 0; s < 6; ++s) {
            bf16x8 ah0 = *(const bf16x8*)(wb + (size_t)((((t0 * 6 + s) * 2) + 0) * 64 + lane) * 8);
            bf16x8 al0 = *(const bf16x8*)(wb + (size_t)((((t0 * 6 + s) * 2) + 1) * 64 + lane) * 8);
            bf16x8 ah1 = *(const bf16x8*)(wb + (size_t)((((t1 * 6 + s) * 2) + 0) * 64 + lane) * 8);
            bf16x8 al1 = *(const bf16x8*)(wb + (size_t)((((t1 * 6 + s) * 2) + 1) * 64 + lane) * 8);
            a0 = __builtin_amdgcn_mfma_f32_32x32x16_bf16(ah0, xh[s], a0, 0, 0, 0);
            a1 = __builtin_amdgcn_mfma_f32_32x32x16_bf16(ah1, xh[s], a1, 0, 0, 0);
            a0 = __builtin_amdgcn_mfma_f32_32x32x16_bf16(al0, xh[s], a0, 0, 0, 0);
            a1 = __builtin_amdgcn_mfma_f32_32x32x16_bf16(al1, xh[s], a1, 0, 0, 0);
            a0 = __builtin_amdgcn_mfma_f32_32x32x16_bf16(ah0, xl[s], a0, 0, 0, 0);
            a1 = __builtin_amdgcn_mfma_f32_32x32x16_bf16(ah1, xl[s], a1, 0, 0, 0);
        }
        __builtin_amdgcn_s_setprio(0);
        // serial scan, ascending code order per lane (first-min tie rule)
        #pragma unroll
        for (int r = 0; r < 16; ++r) {
            float sv = a0[r];
            int   kv = t0 * 32 + (r & 3) + 8 * (r >> 2) + hib * 4;
            if (sv < b1)      { b2 = b1; i2 = i1; b1 = sv; i1 = kv; }
            else if (sv < b2) { b2 = sv; i2 = kv; }
        }
        #pragma unroll
        for (int r = 0; r < 16; ++r) {
            float sv = a1[r];
            int   kv = t1 * 32 + (r & 3) + 8 * (r >> 2) + hib * 4;
            if (sv < b1)      { b2 = b1; i2 = i1; b1 = sv; i1 = kv; }
            else if (sv < b2) { b2 = sv; i2 = kv; }
        }
    }
    {   // merge lane^32 partner (same rows, other hib codes) — validated code
        float ob1 = __shfl_xor(b1, 32);
        int   oi1 = __shfl_xor(i1, 32);
        float ob2 = __shfl_xor(b2, 32);
        int   oi2 = __shfl_xor(i2, 32);
        bool o1_better = (ob1 < b1) || (ob1 == b1 && oi1 < i1);
        if (o1_better) {
            bool mine_better = (b1 < ob2) || (b1 == ob2 && i1 < oi2);
            if (mine_better) { b2 = b1; i2 = i1; } else { b2 = ob2; i2 = oi2; }
            b1 = ob1; i1 = oi1;
        } else {
            if ((ob1 < b2) || (ob1 == b2 && oi1 < i2)) { b2 = ob1; i2 = oi1; }
        }
    }

    // ---- cheap top-2 fp64 recheck (validated; ~1-2% trigger; uniform 96-iter loop) ----
    {
        int grow = row0 + (lane & 31);
        if (lane < 32 && grow < nrows && (b2 - b1 < THR)) {
            const float* xr = emb + (size_t)grow * EMB + m * SDIM;
            const float* ca = cb + ((size_t)m * NCODE + i1) * SDIM;
            const float* cbv = cb + ((size_t)m * NCODE + i2) * SDIM;
            double da = 0.0, db = 0.0;
            for (int kk = 0; kk < SDIM; ++kk) {
                double ea = (double)xr[kk] - (double)ca[kk];
                double eb = (double)xr[kk] - (double)cbv[kk];
                da += ea * ea; db += eb * eb;
            }
            if (db < da || (db == da && i2 < i1)) i1 = i2;
        }
    }

    // ---- gather + coalesced write-out (24 lanes = 384B runs per row) ----
    #pragma unroll
    for (int ii = 0; ii < 12; ++ii) {
        int Q = ii * 64 + lane;                 // 768 = 32 rows x 24 float4
        int r = Q / 24, f = Q % 24;
        int grow = row0 + r;
        int k = __shfl(i1, r);                  // winner held by lane r (<32)
        if (grow < nrows) {
            float4 v = *(const float4*)(cb + ((size_t)m * NCODE + k) * SDIM + f * 4);
            *(float4*)(out + (size_t)grow * EMB + m * SDIM + f * 4) = v;
        }
    }
}

// ---------------- fallback (round-2 kernel, validated) ----------------
__global__ __launch_bounds__(256) void pq_argmin_kernel(
    const float* __restrict__ emb, const float* __restrict__ cb,
    float* __restrict__ out, int nrows)
{
    const int m   = (int)(blockIdx.x & 7);
    const int row = (int)(blockIdx.x >> 3) * 256 + (int)threadIdx.x;
    const float* __restrict__ cbm = cb + (size_t)m * (NCODE * SDIM);
    __shared__ float half_c2[NCODE];
    {
        const int k = (int)threadIdx.x;
        const float* c = cbm + k * SDIM;
        float s = 0.f;
        #pragma unroll
        for (int i = 0; i < SDIM; i += 4) {
            const float4 v = *reinterpret_cast<const float4*>(c + i);
            s = fmaf(v.x, v.x, s); s = fmaf(v.y, v.y, s);
            s = fmaf(v.z, v.z, s); s = fmaf(v.w, v.w, s);
        }
        half_c2[k] = 0.5f * s;
    }
    __syncthreads();
    if (row >= nrows) return;
    float x[SDIM];
    {
        const float* xr = emb + (size_t)row * EMB + m * SDIM;
        #pragma unroll
        for (int i = 0; i < SDIM; i += 4) {
            const float4 v = *reinterpret_cast<const float4*>(xr + i);
            x[i+0] = v.x; x[i+1] = v.y; x[i+2] = v.z; x[i+3] = v.w;
        }
    }
    float best = 3.4e38f, best2 = 3.4e38f;
    int bestk = 0, bestk2 = 0;
    #pragma unroll 1
    for (int k = 0; k < NCODE; k += 4) {
        const float* c0 = cbm + (k + 0) * SDIM;
        const float* c1 = cbm + (k + 1) * SDIM;
        const float* c2 = cbm + (k + 2) * SDIM;
        const float* c3 = cbm + (k + 3) * SDIM;
        float a0 = 0.f, a1 = 0.f, a2 = 0.f, a3 = 0.f;
        #pragma unroll
        for (int i = 0; i < SDIM; i += 4) {
            const float4 v0 = *reinterpret_cast<const float4*>(c0 + i);
            const float4 v1 = *reinterpret_cast<const float4*>(c1 + i);
            const float4 v2 = *reinterpret_cast<const float4*>(c2 + i);
            const float4 v3 = *reinterpret_cast<const float4*>(c3 + i);
            a0 = fmaf(x[i+0], v0.x, a0); a0 = fmaf(x[i+1], v0.y, a0);
            a0 = fmaf(x[i+2], v0.z, a0); a0 = fmaf(x[i+3], v0.w, a0);
            a1 = fmaf(x[i+0], v1.x, a1); a1 = fmaf(x[i+1], v1.y, a1);
            a1 = fmaf(x[i+2], v1.z, a1); a1 = fmaf(x[i+3], v1.w, a1);
            a2 = fmaf(x[i+0], v2.x, a2); a2 = fmaf(x[i+1], v2.y, a2);
            a2 = fmaf(x[i+2], v2.z, a2); a2 = fmaf(x[i+3], v2.w, a2);
            a3 = fmaf(x[i+0], v3.x, a3); a3 = fmaf(x[i+1], v3.y, a3);
            a3 = fmaf(x[i+2], v3.z, a3); a3 = fmaf(x[i+3], v3.w, a3);
        }
        const float s[4] = { half_c2[k+0] - a0, half_c2[k+1] - a1,
                             half_c2[k+2] - a2, half_c2[k+3] - a3 };
        #pragma unroll
        for (int j = 0; j < 4; ++j) {
            if (s[j] < best)       { best2 = best; bestk2 = bestk; best = s[j]; bestk = k + j; }
            else if (s[j] < best2) { best2 = s[j]; bestk2 = k + j; }
        }
    }
    if (best2 - best < 0.02f) {
        const float* ca = cbm + bestk  * SDIM;
        const float* cbv = cbm + bestk2 * SDIM;
        double da = 0.0, db = 0.0;
        for (int i = 0; i < SDIM; ++i) {
            const double ea = (double)x[i] - (double)ca[i];
            const double eb = (double)x[i] - (double)cbv[i];
            da += ea * ea; db += eb * eb;
        }
        if (db < da || (db == da && bestk2 < bestk)) bestk = bestk2;
    }
    const float* cbest = cbm + bestk * SDIM;
    float* o = out + (size_t)row * EMB + m * SDIM;
    #pragma unroll
    for (int i = 0; i < SDIM; i += 4)
        *reinterpret_cast<float4*>(o + i) = *reinterpret_cast<const float4*>(cbest + i);
}

extern "C" void kernel_launch(void* const* d_in, const int* in_sizes, int n_in,
                              void* d_out, int out_size, void* d_ws, size_t ws_size,
                              hipStream_t stream) {
    const float* emb = (const float*)d_in[0];
    const float* cb  = (const float*)d_in[1];
    float* out = (float*)d_out;
    const int nrows = in_sizes[0] / EMB;    // 65536

    if (ws_size < WS_NEEDED) {
        const int rowBlocks = (nrows + 255) / 256;
        pq_argmin_kernel<<<dim3(rowBlocks * NSUB), dim3(256), 0, stream>>>(emb, cb, out, nrows);
        return;
    }

    unsigned short* wsf = (unsigned short*)d_ws;
    float* wsc2 = (float*)((char*)d_ws + WS_FRAG_BYTES);

    pq_prep<<<dim3(NSUB), dim3(256), 0, stream>>>(cb, wsf, wsc2);

    const int rowblks = (nrows + 31) / 32;              // 2048
    const int nwaves  = rowblks * NSUB;                 // 16384
    const int nb      = (nwaves + 1) / 2;               // 8192 blocks of 128
    pq_mfma12<<<dim3(nb), dim3(128), 0, stream>>>(emb, cb, wsf, wsc2, out, nrows, rowblks);
}